// Round 1
// baseline (1627.236 us; speedup 1.0000x reference)
//
#include <hip/hip_runtime.h>

#define QLEN 512
#define MLEN 512
#define KLEN 1024
#define BB   8
#define DMODEL 1024
#define NH   16
#define HD   64
#define NF   384
#define ATT_SCALE 0.125f
#define EPSV 1e-5f

typedef float v4f __attribute__((ext_vector_type(4)));

__device__ __forceinline__ float bf2f(unsigned short u) {
    unsigned int v = ((unsigned int)u) << 16;
    return __builtin_bit_cast(float, v);
}
__device__ __forceinline__ unsigned short f2bf(float f) {
    unsigned int x = __builtin_bit_cast(unsigned int, f);
    x += 0x7fffu + ((x >> 16) & 1u);
    return (unsigned short)(x >> 16);
}

// ---------------------------------------------------------------------------
// Projection GEMM (64x64 tile, BK=16, 4x4 microtile) fused with DPFP epilogue.
// MODE 0: q = h @ Wq^T            -> qf features (bf16)
// MODE 1: k,v = c @ Wkv^T         -> kf features (bf16), v raw (f32)
// A rows are (seq*B + b). Col tile ct: MODE0 head=ct; MODE1 ct<16 k-head,
// ct>=16 v-head (ct-16).
// ---------------------------------------------------------------------------
template<int MODE>
__global__ __launch_bounds__(256)
void proj_kernel(const float* __restrict__ hsrc, const float* __restrict__ mems,
                 const float* __restrict__ W,
                 unsigned short* __restrict__ feat, float* __restrict__ vout)
{
    __shared__ float As[16][68];
    __shared__ float Bs[16][68];
    __shared__ float Cs[64][68];

    const int t  = threadIdx.x;
    const int ty = t >> 4, tx = t & 15;
    const int ct = blockIdx.x;
    const int m0 = blockIdx.y * 64;
    const int n0 = ct * 64;

    const int lr = t >> 2;        // 0..63
    const int lk = (t & 3) << 2;  // 0,4,8,12

    const float* arow;
    {
        int grow = m0 + lr;
        if constexpr (MODE == 0) {
            arow = hsrc + (size_t)grow * DMODEL;
        } else {
            int j = grow >> 3, b = grow & 7;
            arow = (j < MLEN) ? (mems + ((size_t)j * BB + b) * DMODEL)
                              : (hsrc + ((size_t)(j - MLEN) * BB + b) * DMODEL);
        }
    }
    const float* brow = W + (size_t)(n0 + lr) * DMODEL;

    float acc[4][4] = {};

    for (int k0 = 0; k0 < DMODEL; k0 += 16) {
        v4f av = *(const v4f*)(arow + k0 + lk);
        v4f bv = *(const v4f*)(brow + k0 + lk);
        __syncthreads();
        #pragma unroll
        for (int e = 0; e < 4; ++e) { As[lk + e][lr] = av[e]; Bs[lk + e][lr] = bv[e]; }
        __syncthreads();
        #pragma unroll
        for (int kk = 0; kk < 16; ++kk) {
            v4f a = *(const v4f*)&As[kk][ty << 2];
            v4f b = *(const v4f*)&Bs[kk][tx << 2];
            #pragma unroll
            for (int r = 0; r < 4; ++r)
                #pragma unroll
                for (int c = 0; c < 4; ++c)
                    acc[r][c] = fmaf(a[r], b[c], acc[r][c]);
        }
    }

    #pragma unroll
    for (int r = 0; r < 4; ++r)
        #pragma unroll
        for (int c = 0; c < 4; ++c)
            Cs[(ty << 2) + r][(tx << 2) + c] = acc[r][c];
    __syncthreads();

    const int fr  = t >> 2;       // row within tile
    const int p   = t & 3;        // quarter of the feature/dim space
    const int grow = m0 + fr;
    const int seq  = grow >> 3;   // i (MODE0) or j (MODE1)
    const int b    = grow & 7;

    bool is_v; int head;
    if constexpr (MODE == 0) { is_v = false; head = ct; }
    else { is_v = (ct >= NH); head = is_v ? (ct - NH) : ct; }

    if (!is_v) {
        const int slen = (MODE == 0) ? QLEN : KLEN;
        unsigned short* dst = feat + ((size_t)(b * NH + head) * slen + seq) * NF;
        const float* qrow = &Cs[fr][0];
        #pragma unroll
        for (int g = 0; g < 24; ++g) {
            unsigned short tmp[4];
            #pragma unroll
            for (int e = 0; e < 4; ++e) {
                int f  = p * 96 + g * 4 + e;
                int r  = (f >> 7) + 1;    // roll 1..3
                int tt = f & 127;
                int t2 = (tt - r) & 127;
                float xa = (tt < 64) ? fmaxf(qrow[tt], 0.f) : fmaxf(-qrow[tt - 64], 0.f);
                float xb = (t2 < 64) ? fmaxf(qrow[t2], 0.f) : fmaxf(-qrow[t2 - 64], 0.f);
                tmp[e] = f2bf(xa * xb);
            }
            ushort4 pk; pk.x = tmp[0]; pk.y = tmp[1]; pk.z = tmp[2]; pk.w = tmp[3];
            *(ushort4*)(dst + p * 96 + g * 4) = pk;
        }
    } else {
        float* dst = vout + ((size_t)(b * NH + head) * KLEN + seq) * HD;
        #pragma unroll
        for (int l = 0; l < 4; ++l) {
            v4f vv;
            #pragma unroll
            for (int e = 0; e < 4; ++e) vv[e] = Cs[fr][p * 16 + l * 4 + e];
            *(v4f*)(dst + p * 16 + l * 4) = vv;
        }
    }
}

// ---------------------------------------------------------------------------
// Attention: per (b, head, i-tile of 64). Streams j-tiles; score is linear so
// num/den accumulate in one pass (no softmax, no score materialization).
// ---------------------------------------------------------------------------
__global__ __launch_bounds__(256)
void attn_kernel(const unsigned short* __restrict__ qf,
                 const unsigned short* __restrict__ kf,
                 const float* __restrict__ vws,
                 float* __restrict__ avec)
{
    __shared__ float Qs[16][68];
    __shared__ float Ks[16][68];
    __shared__ float Ss[64][65];   // stride 65: scalar access, 2-way max conflict
    __shared__ float Vs[64][68];
    __shared__ float den_s[64];

    const int t  = threadIdx.x;
    const int ty = t >> 4, tx = t & 15;
    const int it = blockIdx.x;
    const int n  = blockIdx.y;
    const int b  = blockIdx.z;
    const int i0 = it * 64;

    const unsigned short* qbase = qf + (size_t)(b * NH + n) * QLEN * NF;
    const unsigned short* kbase = kf + (size_t)(b * NH + n) * KLEN * NF;
    const float* vbase = vws + (size_t)(b * NH + n) * KLEN * HD;

    const int lr = t >> 2;
    const int lf = (t & 3) << 2;

    if (t < 64) den_s[t] = 0.f;

    float num[4][4] = {};

    const int jt_max = min(15, it + 8);
    for (int jt = 0; jt <= jt_max; ++jt) {
        const int j0 = jt * 64;
        float s[4][4] = {};
        for (int f0 = 0; f0 < NF; f0 += 16) {
            ushort4 qv = *(const ushort4*)(qbase + (size_t)(i0 + lr) * NF + f0 + lf);
            ushort4 kv = *(const ushort4*)(kbase + (size_t)(j0 + lr) * NF + f0 + lf);
            __syncthreads();
            Qs[lf + 0][lr] = bf2f(qv.x); Qs[lf + 1][lr] = bf2f(qv.y);
            Qs[lf + 2][lr] = bf2f(qv.z); Qs[lf + 3][lr] = bf2f(qv.w);
            Ks[lf + 0][lr] = bf2f(kv.x); Ks[lf + 1][lr] = bf2f(kv.y);
            Ks[lf + 2][lr] = bf2f(kv.z); Ks[lf + 3][lr] = bf2f(kv.w);
            __syncthreads();
            #pragma unroll
            for (int kk = 0; kk < 16; ++kk) {
                v4f a  = *(const v4f*)&Qs[kk][ty << 2];
                v4f bq = *(const v4f*)&Ks[kk][tx << 2];
                #pragma unroll
                for (int r = 0; r < 4; ++r)
                    #pragma unroll
                    for (int c = 0; c < 4; ++c)
                        s[r][c] = fmaf(a[r], bq[c], s[r][c]);
            }
        }

        const bool diag = (jt == it + 8);   // partial (causal) tile
        float rowsum[4];
        #pragma unroll
        for (int r = 0; r < 4; ++r) {
            rowsum[r] = 0.f;
            #pragma unroll
            for (int c = 0; c < 4; ++c) {
                float sv = s[r][c] * ATT_SCALE;
                if (diag && ((tx << 2) + c) > ((ty << 2) + r)) sv = 0.f;
                rowsum[r] += sv;
                Ss[(ty << 2) + r][(tx << 2) + c] = sv;
            }
        }
        // reduce row sums across the 16 tx lanes (lanes of same ty are adjacent)
        #pragma unroll
        for (int r = 0; r < 4; ++r) {
            float v = rowsum[r];
            v += __shfl_down(v, 8, 16);
            v += __shfl_down(v, 4, 16);
            v += __shfl_down(v, 2, 16);
            v += __shfl_down(v, 1, 16);
            if (tx == 0) den_s[(ty << 2) + r] += v;   // unique writer per row
        }
        // stage V tile
        #pragma unroll
        for (int l = 0; l < 4; ++l) {
            int j = l * 16 + ty;
            *(v4f*)&Vs[j][tx << 2] =
                *(const v4f*)(vbase + (size_t)(j0 + j) * HD + (tx << 2));
        }
        __syncthreads();
        // PV accumulation
        #pragma unroll 8
        for (int jj = 0; jj < 64; ++jj) {
            v4f vv = *(const v4f*)&Vs[jj][tx << 2];
            #pragma unroll
            for (int r = 0; r < 4; ++r) {
                float sv = Ss[(ty << 2) + r][jj];
                #pragma unroll
                for (int c = 0; c < 4; ++c)
                    num[r][c] = fmaf(sv, vv[c], num[r][c]);
            }
        }
        __syncthreads();
    }

    #pragma unroll
    for (int r = 0; r < 4; ++r) {
        float den = den_s[(ty << 2) + r] + EPSV;
        float inv = 1.f / den;
        int i = i0 + (ty << 2) + r;
        v4f o;
        #pragma unroll
        for (int c = 0; c < 4; ++c) o[c] = num[r][c] * inv;
        *(v4f*)(avec + ((size_t)i * BB + b) * DMODEL + n * HD + (tx << 2)) = o;
    }
}

// ---------------------------------------------------------------------------
// x = h + attn_vec @ Wo^T
// ---------------------------------------------------------------------------
__global__ __launch_bounds__(256)
void oproj_kernel(const float* __restrict__ A, const float* __restrict__ W,
                  const float* __restrict__ h, float* __restrict__ xo)
{
    __shared__ float As[16][68];
    __shared__ float Bs[16][68];

    const int t  = threadIdx.x;
    const int ty = t >> 4, tx = t & 15;
    const int m0 = blockIdx.y * 64;
    const int n0 = blockIdx.x * 64;

    const int lr = t >> 2;
    const int lk = (t & 3) << 2;

    const float* arow = A + (size_t)(m0 + lr) * DMODEL;
    const float* brow = W + (size_t)(n0 + lr) * DMODEL;

    float acc[4][4] = {};

    for (int k0 = 0; k0 < DMODEL; k0 += 16) {
        v4f av = *(const v4f*)(arow + k0 + lk);
        v4f bv = *(const v4f*)(brow + k0 + lk);
        __syncthreads();
        #pragma unroll
        for (int e = 0; e < 4; ++e) { As[lk + e][lr] = av[e]; Bs[lk + e][lr] = bv[e]; }
        __syncthreads();
        #pragma unroll
        for (int kk = 0; kk < 16; ++kk) {
            v4f a = *(const v4f*)&As[kk][ty << 2];
            v4f b = *(const v4f*)&Bs[kk][tx << 2];
            #pragma unroll
            for (int r = 0; r < 4; ++r)
                #pragma unroll
                for (int c = 0; c < 4; ++c)
                    acc[r][c] = fmaf(a[r], b[c], acc[r][c]);
        }
    }

    #pragma unroll
    for (int r = 0; r < 4; ++r) {
        int row = m0 + (ty << 2) + r;
        v4f hv = *(const v4f*)(h + (size_t)row * DMODEL + n0 + (tx << 2));
        v4f o;
        #pragma unroll
        for (int c = 0; c < 4; ++c) o[c] = acc[r][c] + hv[c];
        *(v4f*)(xo + (size_t)row * DMODEL + n0 + (tx << 2)) = o;
    }
}

// ---------------------------------------------------------------------------
// Row LayerNorm over DM=1024 (one block of 256 per row).
// ---------------------------------------------------------------------------
__global__ __launch_bounds__(256)
void ln_kernel(const float* __restrict__ x, const float* __restrict__ gamma,
               const float* __restrict__ beta, float* __restrict__ out)
{
    const int row = blockIdx.x;
    const int t = threadIdx.x;
    const float* xr = x + (size_t)row * DMODEL;
    v4f xv = *(const v4f*)(xr + (t << 2));
    float s1 = xv[0] + xv[1] + xv[2] + xv[3];
    float s2 = xv[0]*xv[0] + xv[1]*xv[1] + xv[2]*xv[2] + xv[3]*xv[3];
    #pragma unroll
    for (int off = 32; off > 0; off >>= 1) {
        s1 += __shfl_down(s1, off);
        s2 += __shfl_down(s2, off);
    }
    __shared__ float red[2][4];
    __shared__ float mv[2];
    const int wave = t >> 6;
    if ((t & 63) == 0) { red[0][wave] = s1; red[1][wave] = s2; }
    __syncthreads();
    if (t == 0) {
        float a = red[0][0] + red[0][1] + red[0][2] + red[0][3];
        float q = red[1][0] + red[1][1] + red[1][2] + red[1][3];
        float mu  = a * (1.f / DMODEL);
        float var = q * (1.f / DMODEL) - mu * mu;
        mv[0] = mu;
        mv[1] = rsqrtf(var + EPSV);
    }
    __syncthreads();
    float mu = mv[0], rs = mv[1];
    v4f gv = *(const v4f*)(gamma + (t << 2));
    v4f bv = *(const v4f*)(beta + (t << 2));
    v4f o;
    #pragma unroll
    for (int e = 0; e < 4; ++e) o[e] = (xv[e] - mu) * rs * gv[e] + bv[e];
    *(v4f*)(out + (size_t)row * DMODEL + (t << 2)) = o;
}

extern "C" void kernel_launch(void* const* d_in, const int* in_sizes, int n_in,
                              void* d_out, int out_size, void* d_ws, size_t ws_size,
                              hipStream_t stream)
{
    const float* h     = (const float*)d_in[0];
    const float* mems  = (const float*)d_in[1];
    const float* Wq    = (const float*)d_in[2];
    const float* Wkv   = (const float*)d_in[3];
    const float* Wo    = (const float*)d_in[4];
    const float* gamma = (const float*)d_in[5];
    const float* beta  = (const float*)d_in[6];
    // d_in[7] = attn_mask: causal structure computed analytically, ignored.

    char* ws = (char*)d_ws;
    unsigned short* qf = (unsigned short*)(ws);              // 50,331,648 B
    unsigned short* kf = (unsigned short*)(ws + 50331648);   // 100,663,296 B
    float* vws  = (float*)(ws + 150994944);                  // 33,554,432 B
    float* avec = (float*)(ws + 184549376);                  // 16,777,216 B
    float* xws  = (float*)(ws);                              // reuse qf region

    proj_kernel<0><<<dim3(16, 64), 256, 0, stream>>>(h, nullptr, Wq, qf, nullptr);
    proj_kernel<1><<<dim3(32, 128), 256, 0, stream>>>(h, mems, Wkv, kf, vws);
    attn_kernel<<<dim3(8, 16, 8), 256, 0, stream>>>(qf, kf, vws, avec);
    oproj_kernel<<<dim3(16, 64), 256, 0, stream>>>(avec, Wo, h, xws);
    ln_kernel<<<4096, 256, 0, stream>>>(xws, gamma, beta, (float*)d_out);
}

// Round 2
// 1216.289 us; speedup vs baseline: 1.3379x; 1.3379x over previous
//
#include <hip/hip_runtime.h>

#define QLEN 512
#define MLEN 512
#define KLEN 1024
#define BB   8
#define DMODEL 1024
#define NH   16
#define HD   64
#define NF   384
#define ATT_SCALE 0.125f
#define EPSV 1e-5f

typedef float v4f __attribute__((ext_vector_type(4)));
typedef short bf16x8 __attribute__((ext_vector_type(8)));
typedef unsigned int u32x4 __attribute__((ext_vector_type(4)));

__device__ __forceinline__ float bf2f(unsigned short u) {
    unsigned int v = ((unsigned int)u) << 16;
    return __builtin_bit_cast(float, v);
}
__device__ __forceinline__ unsigned short f2bf(float f) {
    unsigned int x = __builtin_bit_cast(unsigned int, f);
    x += 0x7fffu + ((x >> 16) & 1u);
    return (unsigned short)(x >> 16);
}

// ---------------------------------------------------------------------------
// Projection GEMM (64x64 tile, BK=16, 4x4 microtile) fused with DPFP epilogue.
// MODE 0: q = h @ Wq^T            -> qf features (bf16)
// MODE 1: k,v = c @ Wkv^T         -> kf features (bf16), v bf16 TRANSPOSED
//         vt layout: [b,head][d][KLEN]
// ---------------------------------------------------------------------------
template<int MODE>
__global__ __launch_bounds__(256)
void proj_kernel(const float* __restrict__ hsrc, const float* __restrict__ mems,
                 const float* __restrict__ W,
                 unsigned short* __restrict__ feat, unsigned short* __restrict__ vout)
{
    __shared__ float As[16][68];
    __shared__ float Bs[16][68];
    __shared__ float Cs[64][68];

    const int t  = threadIdx.x;
    const int ty = t >> 4, tx = t & 15;
    const int ct = blockIdx.x;
    const int m0 = blockIdx.y * 64;
    const int n0 = ct * 64;

    const int lr = t >> 2;        // 0..63
    const int lk = (t & 3) << 2;  // 0,4,8,12

    const float* arow;
    {
        int grow = m0 + lr;
        if constexpr (MODE == 0) {
            arow = hsrc + (size_t)grow * DMODEL;
        } else {
            int j = grow >> 3, b = grow & 7;
            arow = (j < MLEN) ? (mems + ((size_t)j * BB + b) * DMODEL)
                              : (hsrc + ((size_t)(j - MLEN) * BB + b) * DMODEL);
        }
    }
    const float* brow = W + (size_t)(n0 + lr) * DMODEL;

    float acc[4][4] = {};

    for (int k0 = 0; k0 < DMODEL; k0 += 16) {
        v4f av = *(const v4f*)(arow + k0 + lk);
        v4f bv = *(const v4f*)(brow + k0 + lk);
        __syncthreads();
        #pragma unroll
        for (int e = 0; e < 4; ++e) { As[lk + e][lr] = av[e]; Bs[lk + e][lr] = bv[e]; }
        __syncthreads();
        #pragma unroll
        for (int kk = 0; kk < 16; ++kk) {
            v4f a = *(const v4f*)&As[kk][ty << 2];
            v4f b = *(const v4f*)&Bs[kk][tx << 2];
            #pragma unroll
            for (int r = 0; r < 4; ++r)
                #pragma unroll
                for (int c = 0; c < 4; ++c)
                    acc[r][c] = fmaf(a[r], b[c], acc[r][c]);
        }
    }

    #pragma unroll
    for (int r = 0; r < 4; ++r)
        #pragma unroll
        for (int c = 0; c < 4; ++c)
            Cs[(ty << 2) + r][(tx << 2) + c] = acc[r][c];
    __syncthreads();

    const int fr  = t >> 2;       // row within tile
    const int p   = t & 3;        // quarter of the feature/dim space
    const int grow = m0 + fr;
    const int seq  = grow >> 3;   // i (MODE0) or j (MODE1)
    const int b    = grow & 7;

    bool is_v; int head;
    if constexpr (MODE == 0) { is_v = false; head = ct; }
    else { is_v = (ct >= NH); head = is_v ? (ct - NH) : ct; }

    if (!is_v) {
        const int slen = (MODE == 0) ? QLEN : KLEN;
        unsigned short* dst = feat + ((size_t)(b * NH + head) * slen + seq) * NF;
        const float* qrow = &Cs[fr][0];
        #pragma unroll
        for (int g = 0; g < 24; ++g) {
            unsigned short tmp[4];
            #pragma unroll
            for (int e = 0; e < 4; ++e) {
                int f  = p * 96 + g * 4 + e;
                int r  = (f >> 7) + 1;    // roll 1..3
                int tt = f & 127;
                int t2 = (tt - r) & 127;
                float xa = (tt < 64) ? fmaxf(qrow[tt], 0.f) : fmaxf(-qrow[tt - 64], 0.f);
                float xb = (t2 < 64) ? fmaxf(qrow[t2], 0.f) : fmaxf(-qrow[t2 - 64], 0.f);
                tmp[e] = f2bf(xa * xb);
            }
            ushort4 pk; pk.x = tmp[0]; pk.y = tmp[1]; pk.z = tmp[2]; pk.w = tmp[3];
            *(ushort4*)(dst + p * 96 + g * 4) = pk;
        }
    } else {
        // V transposed bf16: vout[(b,head)][d][KLEN], d = p*16+e
        unsigned short* dstp = vout + ((size_t)(b * NH + head) * HD) * KLEN + seq;
        #pragma unroll
        for (int e = 0; e < 16; ++e) {
            int d = p * 16 + e;
            dstp[(size_t)d * KLEN] = f2bf(Cs[fr][d]);
        }
    }
}

// ---------------------------------------------------------------------------
// MFMA attention. Block = (it, n, b), 4 waves; wave w owns i rows
// [it*64 + w*16, +16). Streams j-tiles of 64. S via mfma_f32_16x16x32_bf16
// (A=Q frag from global, B=K frag from global). Unnormalized num/den
// accumulation; S round-trips wave-private LDS (f32) to become the PV
// A-operand (cvt_pk_bf16 packing). V read as bf16 transposed fragments.
// No __syncthreads anywhere.
// ---------------------------------------------------------------------------
__global__ __launch_bounds__(256)
void attn_mfma_kernel(const unsigned short* __restrict__ qf,
                      const unsigned short* __restrict__ kf,
                      const unsigned short* __restrict__ vt,
                      float* __restrict__ avec)
{
    __shared__ float Ss[64][68];   // 4 waves x 16 rows, stride 68 (2-way max)

    const int t  = threadIdx.x;
    const int w  = t >> 6;
    const int l  = t & 63;
    const int lj = l & 15;         // col-in-frag / row-in-A-frag
    const int lg = l >> 4;         // k-quarter / row-quarter
    const int it = blockIdx.x;
    const int n  = blockIdx.y;
    const int b  = blockIdx.z;
    const int i0 = it * 64 + w * 16;

    const unsigned short* qbase = qf + (size_t)(b * NH + n) * QLEN * NF;
    const unsigned short* kbase = kf + (size_t)(b * NH + n) * KLEN * NF;
    const unsigned short* vbase = vt + (size_t)(b * NH + n) * HD * KLEN;

    // Q fragments (persist across all j-tiles): A[i=lj][k=32*ks+8*lg+e]
    bf16x8 qfr[12];
    {
        const unsigned short* qrow = qbase + (size_t)(i0 + lj) * NF + lg * 8;
        #pragma unroll
        for (int ks = 0; ks < 12; ++ks)
            qfr[ks] = *(const bf16x8*)(qrow + ks * 32);
    }

    v4f num[4] = {};
    float den[4] = {0.f, 0.f, 0.f, 0.f};

    const int jt_end = it + 8;
    for (int jt = 0; jt <= jt_end; ++jt) {
        const int j0 = jt * 64;

        // ---- S = Q K^T over K=384, 4 j-fragments of 16 ----
        v4f sacc[4] = {};
        #pragma unroll
        for (int jf = 0; jf < 4; ++jf) {
            const unsigned short* krow =
                kbase + (size_t)(j0 + jf * 16 + lj) * NF + lg * 8;
            #pragma unroll
            for (int ks = 0; ks < 12; ++ks) {
                bf16x8 kfr = *(const bf16x8*)(krow + ks * 32);
                sacc[jf] = __builtin_amdgcn_mfma_f32_16x16x32_bf16(
                               qfr[ks], kfr, sacc[jf], 0, 0, 0);
            }
        }

        // ---- mask (causal diag tile), den accum, store raw S to LDS ----
        const bool diag = (jt == jt_end);
        #pragma unroll
        for (int jf = 0; jf < 4; ++jf) {
            #pragma unroll
            for (int r = 0; r < 4; ++r) {
                float sv = sacc[jf][r];
                int li  = 4 * lg + r;        // local row 0..15
                int ljj = jf * 16 + lj;      // local col 0..63
                if (diag && ljj > (w * 16 + li)) sv = 0.f;
                den[r] += sv;
                Ss[w * 16 + li][ljj] = sv;
            }
        }

        // ---- PV: num += P · V  (K=64 -> 2 sub-steps of 32) ----
        #pragma unroll
        for (int kk = 0; kk < 2; ++kk) {
            const float* prow = &Ss[w * 16 + lj][kk * 32 + lg * 8];
            v4f plo = *(const v4f*)prow;
            v4f phi = *(const v4f*)(prow + 4);
            unsigned int w0, w1, w2, w3;
            asm("v_cvt_pk_bf16_f32 %0, %1, %2" : "=v"(w0) : "v"(plo[0]), "v"(plo[1]));
            asm("v_cvt_pk_bf16_f32 %0, %1, %2" : "=v"(w1) : "v"(plo[2]), "v"(plo[3]));
            asm("v_cvt_pk_bf16_f32 %0, %1, %2" : "=v"(w2) : "v"(phi[0]), "v"(phi[1]));
            asm("v_cvt_pk_bf16_f32 %0, %1, %2" : "=v"(w3) : "v"(phi[2]), "v"(phi[3]));
            u32x4 pw = {w0, w1, w2, w3};
            bf16x8 pa = __builtin_bit_cast(bf16x8, pw);
            #pragma unroll
            for (int fd = 0; fd < 4; ++fd) {
                const unsigned short* vrow =
                    vbase + (size_t)(fd * 16 + lj) * KLEN + j0 + kk * 32 + lg * 8;
                bf16x8 vb = *(const bf16x8*)vrow;
                num[fd] = __builtin_amdgcn_mfma_f32_16x16x32_bf16(
                              pa, vb, num[fd], 0, 0, 0);
            }
        }
    }

    // ---- den reduce across 16 lanes of same quarter (j-cols) ----
    #pragma unroll
    for (int r = 0; r < 4; ++r) {
        float v = den[r];
        v += __shfl_xor(v, 1, 16);
        v += __shfl_xor(v, 2, 16);
        v += __shfl_xor(v, 4, 16);
        v += __shfl_xor(v, 8, 16);
        den[r] = v;
    }

    // ---- output: avec[i, b, n*64 + d] = num * scale / (den*scale + eps) ----
    #pragma unroll
    for (int r = 0; r < 4; ++r) {
        float minv = ATT_SCALE / (den[r] * ATT_SCALE + EPSV);
        int gi = i0 + 4 * lg + r;
        float* orow = avec + ((size_t)gi * BB + b) * DMODEL + n * HD;
        #pragma unroll
        for (int fd = 0; fd < 4; ++fd)
            orow[fd * 16 + lj] = num[fd][r] * minv;
    }
}

// ---------------------------------------------------------------------------
// x = h + attn_vec @ Wo^T
// ---------------------------------------------------------------------------
__global__ __launch_bounds__(256)
void oproj_kernel(const float* __restrict__ A, const float* __restrict__ W,
                  const float* __restrict__ h, float* __restrict__ xo)
{
    __shared__ float As[16][68];
    __shared__ float Bs[16][68];

    const int t  = threadIdx.x;
    const int ty = t >> 4, tx = t & 15;
    const int m0 = blockIdx.y * 64;
    const int n0 = blockIdx.x * 64;

    const int lr = t >> 2;
    const int lk = (t & 3) << 2;

    const float* arow = A + (size_t)(m0 + lr) * DMODEL;
    const float* brow = W + (size_t)(n0 + lr) * DMODEL;

    float acc[4][4] = {};

    for (int k0 = 0; k0 < DMODEL; k0 += 16) {
        v4f av = *(const v4f*)(arow + k0 + lk);
        v4f bv = *(const v4f*)(brow + k0 + lk);
        __syncthreads();
        #pragma unroll
        for (int e = 0; e < 4; ++e) { As[lk + e][lr] = av[e]; Bs[lk + e][lr] = bv[e]; }
        __syncthreads();
        #pragma unroll
        for (int kk = 0; kk < 16; ++kk) {
            v4f a = *(const v4f*)&As[kk][ty << 2];
            v4f b = *(const v4f*)&Bs[kk][tx << 2];
            #pragma unroll
            for (int r = 0; r < 4; ++r)
                #pragma unroll
                for (int c = 0; c < 4; ++c)
                    acc[r][c] = fmaf(a[r], b[c], acc[r][c]);
        }
    }

    #pragma unroll
    for (int r = 0; r < 4; ++r) {
        int row = m0 + (ty << 2) + r;
        v4f hv = *(const v4f*)(h + (size_t)row * DMODEL + n0 + (tx << 2));
        v4f o;
        #pragma unroll
        for (int c = 0; c < 4; ++c) o[c] = acc[r][c] + hv[c];
        *(v4f*)(xo + (size_t)row * DMODEL + n0 + (tx << 2)) = o;
    }
}

// ---------------------------------------------------------------------------
// Row LayerNorm over DM=1024 (one block of 256 per row).
// ---------------------------------------------------------------------------
__global__ __launch_bounds__(256)
void ln_kernel(const float* __restrict__ x, const float* __restrict__ gamma,
               const float* __restrict__ beta, float* __restrict__ out)
{
    const int row = blockIdx.x;
    const int t = threadIdx.x;
    const float* xr = x + (size_t)row * DMODEL;
    v4f xv = *(const v4f*)(xr + (t << 2));
    float s1 = xv[0] + xv[1] + xv[2] + xv[3];
    float s2 = xv[0]*xv[0] + xv[1]*xv[1] + xv[2]*xv[2] + xv[3]*xv[3];
    #pragma unroll
    for (int off = 32; off > 0; off >>= 1) {
        s1 += __shfl_down(s1, off);
        s2 += __shfl_down(s2, off);
    }
    __shared__ float red[2][4];
    __shared__ float mv[2];
    const int wave = t >> 6;
    if ((t & 63) == 0) { red[0][wave] = s1; red[1][wave] = s2; }
    __syncthreads();
    if (t == 0) {
        float a = red[0][0] + red[0][1] + red[0][2] + red[0][3];
        float q = red[1][0] + red[1][1] + red[1][2] + red[1][3];
        float mu  = a * (1.f / DMODEL);
        float var = q * (1.f / DMODEL) - mu * mu;
        mv[0] = mu;
        mv[1] = rsqrtf(var + EPSV);
    }
    __syncthreads();
    float mu = mv[0], rs = mv[1];
    v4f gv = *(const v4f*)(gamma + (t << 2));
    v4f bv = *(const v4f*)(beta + (t << 2));
    v4f o;
    #pragma unroll
    for (int e = 0; e < 4; ++e) o[e] = (xv[e] - mu) * rs * gv[e] + bv[e];
    *(v4f*)(out + (size_t)row * DMODEL + (t << 2)) = o;
}

extern "C" void kernel_launch(void* const* d_in, const int* in_sizes, int n_in,
                              void* d_out, int out_size, void* d_ws, size_t ws_size,
                              hipStream_t stream)
{
    const float* h     = (const float*)d_in[0];
    const float* mems  = (const float*)d_in[1];
    const float* Wq    = (const float*)d_in[2];
    const float* Wkv   = (const float*)d_in[3];
    const float* Wo    = (const float*)d_in[4];
    const float* gamma = (const float*)d_in[5];
    const float* beta  = (const float*)d_in[6];
    // d_in[7] = attn_mask: causal structure computed analytically, ignored.

    char* ws = (char*)d_ws;
    unsigned short* qf = (unsigned short*)(ws);              // 50,331,648 B
    unsigned short* kf = (unsigned short*)(ws + 50331648);   // 100,663,296 B
    unsigned short* vt = (unsigned short*)(ws + 150994944);  // 16,777,216 B
    float* avec = (float*)(ws + 167772160);                  // 16,777,216 B
    float* xws  = (float*)(ws);                              // reuse qf region

    proj_kernel<0><<<dim3(16, 64), 256, 0, stream>>>(h, nullptr, Wq, qf, nullptr);
    proj_kernel<1><<<dim3(32, 128), 256, 0, stream>>>(h, mems, Wkv, kf, vt);
    attn_mfma_kernel<<<dim3(8, 16, 8), 256, 0, stream>>>(qf, kf, vt, avec);
    oproj_kernel<<<dim3(16, 64), 256, 0, stream>>>(avec, Wo, h, xws);
    ln_kernel<<<4096, 256, 0, stream>>>(xws, gamma, beta, (float*)d_out);
}

// Round 3
// 360.842 us; speedup vs baseline: 4.5095x; 3.3707x over previous
//
#include <hip/hip_runtime.h>

#define QLEN 512
#define MLEN 512
#define KLEN 1024
#define BB   8
#define DMODEL 1024
#define NH   16
#define HD   64
#define NF   384
#define ATT_SCALE 0.125f
#define EPSV 1e-5f

typedef float v4f __attribute__((ext_vector_type(4)));
typedef short bf16x8 __attribute__((ext_vector_type(8)));
typedef unsigned int u32x4 __attribute__((ext_vector_type(4)));

__device__ __forceinline__ unsigned short f2bf(float f) {
    unsigned int x = __builtin_bit_cast(unsigned int, f);
    x += 0x7fffu + ((x >> 16) & 1u);
    return (unsigned short)(x >> 16);
}

__device__ __forceinline__ void gll16(const void* g, void* l) {
    __builtin_amdgcn_global_load_lds(
        (const __attribute__((address_space(1))) unsigned int*)g,
        (__attribute__((address_space(3))) unsigned int*)l, 16, 0, 0);
}

// ---------------------------------------------------------------------------
// f32 -> bf16 convert (RNE via v_cvt_pk_bf16_f32), 4 elems/thread
// ---------------------------------------------------------------------------
__global__ __launch_bounds__(256)
void cvt_bf16_kernel(const float* __restrict__ src, unsigned short* __restrict__ dst)
{
    int i = (blockIdx.x * 256 + threadIdx.x) * 4;
    v4f v = *(const v4f*)(src + i);
    unsigned int p0, p1;
    asm("v_cvt_pk_bf16_f32 %0, %1, %2" : "=v"(p0) : "v"(v[0]), "v"(v[1]));
    asm("v_cvt_pk_bf16_f32 %0, %1, %2" : "=v"(p1) : "v"(v[2]), "v"(v[3]));
    uint2 u; u.x = p0; u.y = p1;
    *(uint2*)(dst + i) = u;
}

// ---------------------------------------------------------------------------
// MFMA GEMM: C[64x64] = A[M][1024]bf16 . B[N][1024]bf16 ^T, BK=64, 4 waves
// (each 32x32). LDS tiles staged by global_load_lds w/ pre-swizzled source
// (XOR chunk^row&7); ds_read_b128 frag reads use the same XOR.
// MODE 0: q-proj  -> DPFP features (bf16)
// MODE 1: kv-proj -> k DPFP features + v bf16 transposed [b,h][d][KLEN]
// MODE 2: o-proj  -> xo = C + h (f32)
// ---------------------------------------------------------------------------
template<int MODE>
__global__ __launch_bounds__(256)
void mm_kernel(const unsigned short* __restrict__ Abf,
               const unsigned short* __restrict__ Bbf,
               const float* __restrict__ hres,
               unsigned short* __restrict__ feat,
               unsigned short* __restrict__ vout,
               float* __restrict__ xo)
{
    __shared__ unsigned short As[64 * 64];
    __shared__ unsigned short Bs[64 * 64];
    __shared__ float Cs[64][68];

    const int t  = threadIdx.x;
    const int w  = t >> 6;
    const int l  = t & 63;
    const int lj = l & 15;
    const int lg = l >> 4;
    const int m0 = blockIdx.x * 64;
    const int ct = blockIdx.y;
    const int n0 = ct * 64;
    const int wr = w >> 1, wc = w & 1;

    const int arow_l = l >> 3;                      // row-in-8 group
    const int aswz   = ((l & 7) ^ (l >> 3)) * 16;   // swizzled chunk byte off

    v4f acc[2][2] = {};

    for (int s = 0; s < 16; ++s) {
        const int k0b = s * 128;   // byte offset within a 2048B row
        __syncthreads();
        #pragma unroll
        for (int ii = 0; ii < 2; ++ii) {
            int inst = w + ii * 4;
            gll16((const char*)Abf + (size_t)(m0 + inst * 8 + arow_l) * 2048 + k0b + aswz,
                  (char*)As + inst * 1024);
            gll16((const char*)Bbf + (size_t)(n0 + inst * 8 + arow_l) * 2048 + k0b + aswz,
                  (char*)Bs + inst * 1024);
        }
        __syncthreads();
        #pragma unroll
        for (int ks = 0; ks < 2; ++ks) {
            bf16x8 af[2], bfr[2];
            #pragma unroll
            for (int m = 0; m < 2; ++m) {
                int row = wr * 32 + m * 16 + lj;
                af[m] = *(const bf16x8*)((const char*)As + row * 128 +
                                         (((ks * 4 + lg) ^ (row & 7)) * 16));
            }
            #pragma unroll
            for (int nn = 0; nn < 2; ++nn) {
                int row = wc * 32 + nn * 16 + lj;
                bfr[nn] = *(const bf16x8*)((const char*)Bs + row * 128 +
                                           (((ks * 4 + lg) ^ (row & 7)) * 16));
            }
            #pragma unroll
            for (int m = 0; m < 2; ++m)
                #pragma unroll
                for (int nn = 0; nn < 2; ++nn)
                    acc[m][nn] = __builtin_amdgcn_mfma_f32_16x16x32_bf16(
                                     af[m], bfr[nn], acc[m][nn], 0, 0, 0);
        }
    }

    #pragma unroll
    for (int m = 0; m < 2; ++m)
        #pragma unroll
        for (int nn = 0; nn < 2; ++nn)
            #pragma unroll
            for (int r = 0; r < 4; ++r)
                Cs[wr * 32 + m * 16 + 4 * lg + r][wc * 32 + nn * 16 + lj] = acc[m][nn][r];
    __syncthreads();

    const int fr = t >> 2;        // row within tile
    const int p  = t & 3;         // quarter

    if constexpr (MODE == 2) {
        int row = m0 + fr;
        #pragma unroll
        for (int ll = 0; ll < 4; ++ll) {
            v4f hv = *(const v4f*)(hres + (size_t)row * DMODEL + n0 + p * 16 + ll * 4);
            v4f cv = *(const v4f*)&Cs[fr][p * 16 + ll * 4];
            v4f o = cv + hv;
            *(v4f*)(xo + (size_t)row * DMODEL + n0 + p * 16 + ll * 4) = o;
        }
        return;
    }

    const int grow = m0 + fr;
    const int seq  = grow >> 3;
    const int b    = grow & 7;

    bool is_v; int head;
    if constexpr (MODE == 0) { is_v = false; head = ct; }
    else { is_v = (ct >= NH); head = is_v ? (ct - NH) : ct; }

    if (!is_v) {
        const int slen = (MODE == 0) ? QLEN : KLEN;
        unsigned short* dst = feat + ((size_t)(b * NH + head) * slen + seq) * NF;
        const float* qrow = &Cs[fr][0];
        #pragma unroll
        for (int g = 0; g < 24; ++g) {
            unsigned short tmp[4];
            #pragma unroll
            for (int e = 0; e < 4; ++e) {
                int f  = p * 96 + g * 4 + e;
                int r  = (f >> 7) + 1;
                int tt = f & 127;
                int t2 = (tt - r) & 127;
                float xa = (tt < 64) ? fmaxf(qrow[tt], 0.f) : fmaxf(-qrow[tt - 64], 0.f);
                float xb = (t2 < 64) ? fmaxf(qrow[t2], 0.f) : fmaxf(-qrow[t2 - 64], 0.f);
                tmp[e] = f2bf(xa * xb);
            }
            ushort4 pk; pk.x = tmp[0]; pk.y = tmp[1]; pk.z = tmp[2]; pk.w = tmp[3];
            *(ushort4*)(dst + p * 96 + g * 4) = pk;
        }
    } else {
        unsigned short* dstp = vout + ((size_t)(b * NH + head) * HD) * KLEN + seq;
        #pragma unroll
        for (int e = 0; e < 16; ++e) {
            int d = p * 16 + e;
            dstp[(size_t)d * KLEN] = f2bf(Cs[fr][d]);
        }
    }
}

// ---------------------------------------------------------------------------
// MFMA attention, K/V LDS-staged per j-tile (shared by 4 waves).
// Block = (n, it, b); wave w owns i-rows [it*64+w*16, +16).
// ---------------------------------------------------------------------------
__global__ __launch_bounds__(256)
void attn_mfma_kernel(const unsigned short* __restrict__ qf,
                      const unsigned short* __restrict__ kf,
                      const unsigned short* __restrict__ vt,
                      unsigned short* __restrict__ avec)
{
    __shared__ unsigned short Ks[64 * 384];   // 48KB, rows 768B, swizzled
    __shared__ unsigned short Vs[64 * 64];    // 8KB, rows(d) 128B, swizzled
    __shared__ float Ss[64][68];

    const int t  = threadIdx.x;
    const int w  = t >> 6;
    const int l  = t & 63;
    const int lj = l & 15;
    const int lg = l >> 4;
    const int n  = blockIdx.x;
    const int it = blockIdx.y;
    const int b  = blockIdx.z;
    const int i0 = it * 64 + w * 16;

    const unsigned short* qbase = qf + (size_t)(b * NH + n) * QLEN * NF;
    const unsigned short* kbase = kf + (size_t)(b * NH + n) * KLEN * NF;
    const unsigned short* vbase = vt + (size_t)(b * NH + n) * HD * KLEN;

    // per-lane pre-swizzled staging source offsets (bytes within tile)
    int koff[12];
    #pragma unroll
    for (int u = 0; u < 12; ++u) {
        int L   = (w * 12 + u) * 1024 + l * 16;
        int row = L / 768;
        int cb  = (L - row * 768) >> 4;
        int swz = (cb & ~7) | ((cb & 7) ^ (row & 7));
        koff[u] = row * 768 + swz * 16;
    }
    int voff[2];
    #pragma unroll
    for (int uu = 0; uu < 2; ++uu) {
        int d = (w * 2 + uu) * 8 + (l >> 3);
        int c = (l & 7) ^ (l >> 3);
        voff[uu] = d * (KLEN * 2) + c * 16;
    }

    // Q fragments persist across all j-tiles
    bf16x8 qfr[12];
    {
        const unsigned short* qrow = qbase + (size_t)(i0 + lj) * NF + lg * 8;
        #pragma unroll
        for (int ks = 0; ks < 12; ++ks)
            qfr[ks] = *(const bf16x8*)(qrow + ks * 32);
    }

    v4f num[4] = {};
    float den[4] = {0.f, 0.f, 0.f, 0.f};

    const int jt_end = it + 8;
    for (int jt = 0; jt <= jt_end; ++jt) {
        const int j0 = jt * 64;
        __syncthreads();
        // ---- stage K (rows contiguous: 48KB) and V^T tile (8KB) ----
        const char* ktile = (const char*)(kbase + (size_t)j0 * NF);
        #pragma unroll
        for (int u = 0; u < 12; ++u)
            gll16(ktile + koff[u], (char*)Ks + (w * 12 + u) * 1024);
        const char* vtile = (const char*)vbase + j0 * 2;
        #pragma unroll
        for (int uu = 0; uu < 2; ++uu)
            gll16(vtile + voff[uu], (char*)Vs + (w * 2 + uu) * 1024);
        __syncthreads();

        // ---- S = Q K^T (K frags from LDS) ----
        v4f sacc[4] = {};
        #pragma unroll
        for (int jf = 0; jf < 4; ++jf) {
            const int row = jf * 16 + lj;
            const char* krow = (const char*)Ks + row * 768;
            #pragma unroll
            for (int ks = 0; ks < 12; ++ks) {
                int c   = ks * 4 + lg;
                int swz = (c & ~7) | ((c & 7) ^ (row & 7));
                bf16x8 kfr = *(const bf16x8*)(krow + swz * 16);
                sacc[jf] = __builtin_amdgcn_mfma_f32_16x16x32_bf16(
                               qfr[ks], kfr, sacc[jf], 0, 0, 0);
            }
        }

        // ---- mask, den accumulate, S -> wave-private LDS ----
        const bool diag = (jt == jt_end);
        #pragma unroll
        for (int jf = 0; jf < 4; ++jf) {
            #pragma unroll
            for (int r = 0; r < 4; ++r) {
                float sv = sacc[jf][r];
                int li  = 4 * lg + r;
                int ljj = jf * 16 + lj;
                if (diag && ljj > (w * 16 + li)) sv = 0.f;
                den[r] += sv;
                Ss[w * 16 + li][ljj] = sv;
            }
        }

        // ---- PV: num += S . V ----
        #pragma unroll
        for (int kk = 0; kk < 2; ++kk) {
            const float* prow = &Ss[w * 16 + lj][kk * 32 + lg * 8];
            v4f plo = *(const v4f*)prow;
            v4f phi = *(const v4f*)(prow + 4);
            unsigned int w0, w1, w2, w3;
            asm("v_cvt_pk_bf16_f32 %0, %1, %2" : "=v"(w0) : "v"(plo[0]), "v"(plo[1]));
            asm("v_cvt_pk_bf16_f32 %0, %1, %2" : "=v"(w1) : "v"(plo[2]), "v"(plo[3]));
            asm("v_cvt_pk_bf16_f32 %0, %1, %2" : "=v"(w2) : "v"(phi[0]), "v"(phi[1]));
            asm("v_cvt_pk_bf16_f32 %0, %1, %2" : "=v"(w3) : "v"(phi[2]), "v"(phi[3]));
            u32x4 pw = {w0, w1, w2, w3};
            bf16x8 pa = __builtin_bit_cast(bf16x8, pw);
            #pragma unroll
            for (int fd = 0; fd < 4; ++fd) {
                int row = fd * 16 + lj;
                int swz = (kk * 4 + lg) ^ (row & 7);
                bf16x8 vb = *(const bf16x8*)((const char*)Vs + row * 128 + swz * 16);
                num[fd] = __builtin_amdgcn_mfma_f32_16x16x32_bf16(
                              pa, vb, num[fd], 0, 0, 0);
            }
        }
    }

    // ---- den reduce across the 16 lanes of each group ----
    #pragma unroll
    for (int r = 0; r < 4; ++r) {
        float v = den[r];
        v += __shfl_xor(v, 1, 16);
        v += __shfl_xor(v, 2, 16);
        v += __shfl_xor(v, 4, 16);
        v += __shfl_xor(v, 8, 16);
        den[r] = v;
    }

    // ---- output bf16: avec[(i*8+b)][n*64+d] ----
    #pragma unroll
    for (int r = 0; r < 4; ++r) {
        float minv = ATT_SCALE / (den[r] * ATT_SCALE + EPSV);
        int gi = i0 + 4 * lg + r;
        unsigned short* orow = avec + ((size_t)gi * BB + b) * DMODEL + n * HD;
        #pragma unroll
        for (int fd = 0; fd < 4; ++fd)
            orow[fd * 16 + lj] = f2bf(num[fd][r] * minv);
    }
}

// ---------------------------------------------------------------------------
// Row LayerNorm over DM=1024 (one block of 256 per row).
// ---------------------------------------------------------------------------
__global__ __launch_bounds__(256)
void ln_kernel(const float* __restrict__ x, const float* __restrict__ gamma,
               const float* __restrict__ beta, float* __restrict__ out)
{
    const int row = blockIdx.x;
    const int t = threadIdx.x;
    const float* xr = x + (size_t)row * DMODEL;
    v4f xv = *(const v4f*)(xr + (t << 2));
    float s1 = xv[0] + xv[1] + xv[2] + xv[3];
    float s2 = xv[0]*xv[0] + xv[1]*xv[1] + xv[2]*xv[2] + xv[3]*xv[3];
    #pragma unroll
    for (int off = 32; off > 0; off >>= 1) {
        s1 += __shfl_down(s1, off);
        s2 += __shfl_down(s2, off);
    }
    __shared__ float red[2][4];
    __shared__ float mv[2];
    const int wave = t >> 6;
    if ((t & 63) == 0) { red[0][wave] = s1; red[1][wave] = s2; }
    __syncthreads();
    if (t == 0) {
        float a = red[0][0] + red[0][1] + red[0][2] + red[0][3];
        float q = red[1][0] + red[1][1] + red[1][2] + red[1][3];
        float mu  = a * (1.f / DMODEL);
        float var = q * (1.f / DMODEL) - mu * mu;
        mv[0] = mu;
        mv[1] = rsqrtf(var + EPSV);
    }
    __syncthreads();
    float mu = mv[0], rs = mv[1];
    v4f gv = *(const v4f*)(gamma + (t << 2));
    v4f bv = *(const v4f*)(beta + (t << 2));
    v4f o;
    #pragma unroll
    for (int e = 0; e < 4; ++e) o[e] = (xv[e] - mu) * rs * gv[e] + bv[e];
    *(v4f*)(out + (size_t)row * DMODEL + (t << 2)) = o;
}

extern "C" void kernel_launch(void* const* d_in, const int* in_sizes, int n_in,
                              void* d_out, int out_size, void* d_ws, size_t ws_size,
                              hipStream_t stream)
{
    const float* h     = (const float*)d_in[0];
    const float* mems  = (const float*)d_in[1];
    const float* Wq    = (const float*)d_in[2];
    const float* Wkv   = (const float*)d_in[3];
    const float* Wo    = (const float*)d_in[4];
    const float* gamma = (const float*)d_in[5];
    const float* beta  = (const float*)d_in[6];
    // d_in[7] = attn_mask: causal structure computed analytically, ignored.

    char* ws = (char*)d_ws;
    unsigned short* qf   = (unsigned short*)(ws);             // 50,331,648 B
    unsigned short* kf   = (unsigned short*)(ws + 50331648);  // 100,663,296 B
    unsigned short* vt   = (unsigned short*)(ws + 150994944); // 16,777,216 B
    unsigned short* cbf  = (unsigned short*)(ws + 167772160); // 16,777,216 B
    unsigned short* hbf  = cbf + (size_t)4096 * 1024;         // h rows of c
    unsigned short* avec = cbf;                               // overlay (8MB), cbf dead
    float* xws = (float*)(ws);                                // overlay qf (16MB)

    // weights bf16 scratch inside d_out (dead until ln_kernel rewrites it)
    unsigned short* wqb  = (unsigned short*)d_out;            // 1,048,576 el
    unsigned short* wkvb = wqb + 1048576;                     // 2,097,152 el
    unsigned short* wob  = wkvb + 2097152;                    // 1,048,576 el

    cvt_bf16_kernel<<<4096, 256, 0, stream>>>(mems, cbf);
    cvt_bf16_kernel<<<4096, 256, 0, stream>>>(h, hbf);
    cvt_bf16_kernel<<<1024, 256, 0, stream>>>(Wq, wqb);
    cvt_bf16_kernel<<<2048, 256, 0, stream>>>(Wkv, wkvb);
    cvt_bf16_kernel<<<1024, 256, 0, stream>>>(Wo, wob);

    mm_kernel<0><<<dim3(64, 16), 256, 0, stream>>>(hbf, wqb, nullptr, qf, nullptr, nullptr);
    mm_kernel<1><<<dim3(128, 32), 256, 0, stream>>>(cbf, wkvb, nullptr, kf, vt, nullptr);
    attn_mfma_kernel<<<dim3(16, 8, 8), 256, 0, stream>>>(qf, kf, vt, avec);
    mm_kernel<2><<<dim3(64, 16), 256, 0, stream>>>(avec, wob, h, nullptr, nullptr, xws);
    ln_kernel<<<4096, 256, 0, stream>>>(xws, gamma, beta, (float*)d_out);
}